// Round 13
// baseline (222.765 us; speedup 1.0000x reference)
//
#include <hip/hip_runtime.h>

// AttentionModule: B=16, C=512, H=W=64 (P=4096), nh=8, dh=64.
//   G_b = X_b X_b^T ; s_b = X_b 1
//   att_n * 8 = Wq_n G Wk_n^T + (Wq_n s) bk_n^T + bq_n (Wk_n s)^T + P bq_n bk_n^T
//   P_n = softmax_rows(att_n) ; M[:, nblk] = Wo_n P_n ; out = (M+I) X + bo
// R13: (1) prep stores NONTEMPORAL (both xbf+Xt) — tests L2 write-allocate
//      thrash hypothesis; (2) Gram split-K 8 (1280 blocks, better residency).

typedef unsigned short ushort_t;
typedef __attribute__((ext_vector_type(8))) short bf16x8;
typedef __attribute__((ext_vector_type(4))) float f32x4;
typedef __attribute__((ext_vector_type(4))) unsigned short us4;
typedef __attribute__((ext_vector_type(8))) unsigned short us8;

#define NB 16
#define NC 512
#define NP 4096
#define NHD 8
#define DH 64

#define BM 128
#define BN 128
#define BKK 64

__device__ inline ushort_t f2bf(float f) {
  unsigned int u = __float_as_uint(f);
  u += 0x7FFFu + ((u >> 16) & 1u);
  return (ushort_t)(u >> 16);
}
__device__ inline float bf2f(ushort_t h) {
  return __uint_as_float(((unsigned int)h) << 16);
}
__device__ inline ushort_t f2h(float f) {
  _Float16 h = (_Float16)f;
  return *(ushort_t*)&h;
}
__device__ inline float h2f(ushort_t u) {
  _Float16 h;
  *(ushort_t*)&h = u;
  return (float)h;
}

__device__ inline void gld_lds16(const void* g, void* l) {
  __builtin_amdgcn_global_load_lds(
      (const __attribute__((address_space(1))) unsigned int*)g,
      (__attribute__((address_space(3))) unsigned int*)l, 16, 0, 0);
}

// ---------------- MFMA bt-GEMM: C[m,n] = sum_k A[m,k]*B[n,k] ----------------
// mode 1: C fp32 + bias[row], scalar NONTEMPORAL stores.
// mode 2: C fp32. mode 3: C split-bf16 hi/lo (lo at +4194304 elements).
// mode 4: C fp16 (Gram partials).
// flags bit0: XCD swizzle within z. bit1: triangle split-K8 Gram (grid x=10,z=128).
// bit2: final-GEMM decode (1-D grid 2048, XCD-chunked, n-groups of 16).
// bit3: B operand is [n/128][k/64][128][64]-tiled (8192 elems/tile).
__global__ __launch_bounds__(256, 4) void k_mfma_bt(
    const ushort_t* __restrict__ A, const ushort_t* __restrict__ B,
    void* __restrict__ Cv, const float* __restrict__ bias,
    int lda, int ldb, int ldc, long long sA, long long sB, long long sC,
    int Kper, int mode, int flags) {
  __shared__ __align__(128) ushort_t As[BM * BKK];
  __shared__ __align__(128) ushort_t Bs[BN * BKK];
  int m0, n0;
  long long zc;
  const ushort_t *Ab, *Bb;
  if (flags & 4) {
    int id = blockIdx.x;                               // 2048 blocks
    int nf = (id & 7) * 256 + (id >> 3);               // XCD-chunked bijection
    int z = nf >> 7;                                   // batch (2 per XCD)
    int r = nf & 127;
    int ng = r >> 6;                                   // n-group of 16
    int m = (r >> 4) & 3;
    int nn = ng * 16 + (r & 15);                       // n fastest within group
    m0 = m * BM; n0 = nn * BN;
    Ab = A + z * sA; Bb = B + z * sB;
    zc = (long long)z * sC;
  } else if (flags & 2) {
    int flat = blockIdx.x + 10 * blockIdx.z;          // 1280 blocks
    int nf = (flat & 7) * 160 + (flat >> 3);          // XCD-chunked bijection
    int z2 = nf / 10, tile = nf - z2 * 10;            // z2: 0..127
    int bb = z2 >> 3, sp = z2 & 7;                    // 8-way split-K
    int tm = (0x1A449000u >> (tile * 3)) & 7;         // {0,0,0,0,1,1,1,2,2,3}
    int tn = (0x1B4D1688u >> (tile * 3)) & 7;         // {0,1,2,3,1,2,3,2,3,3}
    m0 = tm * BM; n0 = tn * BN;
    Ab = A + bb * sA + (long long)sp * Kper;
    Bb = B + bb * sB + (long long)sp * Kper;
    zc = (long long)z2 * sC;
  } else {
    int bx = blockIdx.x, by = blockIdx.y;
    if (flags & 1) {
      int nxy = gridDim.x * gridDim.y;
      int id = bx + gridDim.x * by;
      int nid = (id & 7) * (nxy >> 3) + (id >> 3);
      bx = nid % gridDim.x; by = nid / gridDim.x;
    }
    m0 = by * BM; n0 = bx * BN;
    Ab = A + blockIdx.z * sA;
    Bb = B + blockIdx.z * sB;
    zc = (long long)blockIdx.z * sC;
  }
  int t = threadIdx.x;
  int lane = t & 63, w = t >> 6;
  int wr = w >> 1, wc = w & 1;
  int l15 = lane & 15, l4 = lane >> 4;
  int sr = lane >> 3, scc = lane & 7;

  f32x4 zero = {0.f, 0.f, 0.f, 0.f};
  f32x4 acc[4][4];
#pragma unroll
  for (int i = 0; i < 4; ++i)
#pragma unroll
    for (int j = 0; j < 4; ++j) acc[i][j] = zero;

  for (int k0 = 0; k0 < Kper; k0 += BKK) {
#pragma unroll
    for (int i = 0; i < 4; ++i) {
      int slab = w * 4 + i;
      int r = slab * 8 + sr;
      int kc = scc ^ (r & 7);   // pre-swizzled source chunk (involution)
      gld_lds16(Ab + (size_t)(m0 + r) * lda + k0 + kc * 8, &As[slab * 512]);
      if (flags & 8) {
        gld_lds16(Bb + ((size_t)((n0 >> 7) * 8 + (k0 >> 6))) * 8192 + r * 64 + kc * 8,
                  &Bs[slab * 512]);
      } else {
        gld_lds16(Bb + (size_t)(n0 + r) * ldb + k0 + kc * 8, &Bs[slab * 512]);
      }
    }
    __syncthreads();
#pragma unroll
    for (int kf = 0; kf < 2; ++kf) {
      bf16x8 av[4], bv[4];
#pragma unroll
      for (int i = 0; i < 4; ++i) {
        int r = wr * 64 + i * 16 + l15;
        int c = (kf * 4 + l4) ^ (r & 7);
        av[i] = *(const bf16x8*)&As[r * 64 + c * 8];
        int rn = wc * 64 + i * 16 + l15;
        int cn = (kf * 4 + l4) ^ (rn & 7);
        bv[i] = *(const bf16x8*)&Bs[rn * 64 + cn * 8];
      }
#pragma unroll
      for (int i = 0; i < 4; ++i)
#pragma unroll
        for (int j = 0; j < 4; ++j)
          acc[i][j] = __builtin_amdgcn_mfma_f32_16x16x32_bf16(av[i], bv[j],
                                                              acc[i][j], 0, 0, 0);
    }
    __syncthreads();
  }

  if (mode == 3) {
    ushort_t* C = (ushort_t*)Cv + zc;
#pragma unroll
    for (int i = 0; i < 4; ++i)
#pragma unroll
      for (int j = 0; j < 4; ++j)
#pragma unroll
        for (int rr = 0; rr < 4; ++rr) {
          int grow = m0 + wr * 64 + i * 16 + l4 * 4 + rr;
          int gcol = n0 + wc * 64 + j * 16 + l15;
          float v = acc[i][j][rr];
          ushort_t hi = f2bf(v);
          C[(size_t)grow * ldc + gcol] = hi;
          C[4194304 + (size_t)grow * ldc + gcol] = f2bf(v - bf2f(hi));
        }
  } else if (mode == 4) {
    ushort_t* C = (ushort_t*)Cv + zc;
#pragma unroll
    for (int i = 0; i < 4; ++i)
#pragma unroll
      for (int j = 0; j < 4; ++j)
#pragma unroll
        for (int rr = 0; rr < 4; ++rr) {
          int grow = m0 + wr * 64 + i * 16 + l4 * 4 + rr;
          int gcol = n0 + wc * 64 + j * 16 + l15;
          C[(size_t)grow * ldc + gcol] = f2h(acc[i][j][rr]);
        }
  } else if (mode == 1) {
    float* C = (float*)Cv + zc;
#pragma unroll
    for (int i = 0; i < 4; ++i)
#pragma unroll
      for (int j = 0; j < 4; ++j)
#pragma unroll
        for (int rr = 0; rr < 4; ++rr) {
          int grow = m0 + wr * 64 + i * 16 + l4 * 4 + rr;
          int gcol = n0 + wc * 64 + j * 16 + l15;
          __builtin_nontemporal_store(acc[i][j][rr] + bias[grow],
                                      &C[(size_t)grow * ldc + gcol]);
        }
  } else {
    float* C = (float*)Cv + zc;
#pragma unroll
    for (int i = 0; i < 4; ++i)
#pragma unroll
      for (int j = 0; j < 4; ++j)
#pragma unroll
        for (int rr = 0; rr < 4; ++rr) {
          int grow = m0 + wr * 64 + i * 16 + l4 * 4 + rr;
          int gcol = n0 + wc * 64 + j * 16 + l15;
          C[(size_t)grow * ldc + gcol] = acc[i][j][rr];
        }
  }
}

// ------- prep: X fp32 -> Xbf [c][p], Xt TILED (bf16), partial row sums -----
// Nontemporal dual stores: avoid L2 write-allocate thrash vs the x read stream.
__global__ __launch_bounds__(256) void k_prep(const float* __restrict__ x,
                                              ushort_t* __restrict__ xbf,
                                              ushort_t* __restrict__ xt,
                                              float* __restrict__ sPart) {
  __shared__ float tile[64][65];
  int b = blockIdx.z;
  const float* xb = x + (size_t)b * NC * NP;
  int t = threadIdx.x;
  int pp0 = blockIdx.x * 64, cc0 = blockIdx.y * 64;
#pragma unroll
  for (int i = 0; i < 4; ++i) {
    int idx = i * 256 + t;
    int r = idx >> 4, q = idx & 15;
    float4 v = *reinterpret_cast<const float4*>(
        xb + (size_t)(cc0 + r) * NP + pp0 + q * 4);
    us4 u = {f2bf(v.x), f2bf(v.y), f2bf(v.z), f2bf(v.w)};
    __builtin_nontemporal_store(
        u, reinterpret_cast<us4*>(
               &xbf[((size_t)b * NC + cc0 + r) * NP + pp0 + q * 4]));
    tile[r][q * 4 + 0] = v.x; tile[r][q * 4 + 1] = v.y;
    tile[r][q * 4 + 2] = v.z; tile[r][q * 4 + 3] = v.w;
  }
  __syncthreads();
  {
    int r = t >> 2, q = t & 3;
    float ps = 0.f;
#pragma unroll
    for (int i = 0; i < 16; ++i) ps += tile[r][q * 16 + i];
    ps += __shfl_down(ps, 1, 64);
    ps += __shfl_down(ps, 2, 64);
    if (q == 0)
      sPart[(size_t)blockIdx.x * (NB * NC) + b * NC + cc0 + r] = ps;
  }
  {
    int p = t >> 2, cg = t & 3;
    us8 lo, hi;
#pragma unroll
    for (int i = 0; i < 8; ++i) lo[i] = f2bf(tile[cg * 16 + i][p]);
#pragma unroll
    for (int i = 0; i < 8; ++i) hi[i] = f2bf(tile[cg * 16 + 8 + i][p]);
    int prow = ((blockIdx.x & 1) << 6) + p;
    ushort_t* dst =
        &xt[((((size_t)b * 32 + (blockIdx.x >> 1)) * 8 + blockIdx.y)) * 8192 +
            (size_t)prow * 64 + cg * 16];
    __builtin_nontemporal_store(lo, reinterpret_cast<us8*>(dst));
    __builtin_nontemporal_store(hi, reinterpret_cast<us8*>(dst + 8));
  }
}

__global__ __launch_bounds__(256) void k_sreduce(const float* __restrict__ sPart,
                                                 float* __restrict__ s) {
  int idx = blockIdx.x * 256 + threadIdx.x;
  float a = 0.f;
  for (int pb = 0; pb < 64; ++pb) a += sPart[(size_t)pb * (NB * NC) + idx];
  s[idx] = a;
}

__global__ __launch_bounds__(256) void k_cvtw(
    const float* __restrict__ wq, const float* __restrict__ wk,
    const float* __restrict__ wo, ushort_t* __restrict__ q,
    ushort_t* __restrict__ k, ushort_t* __restrict__ o) {
  int i = blockIdx.x * 256 + threadIdx.x;
  q[i] = f2bf(wq[i]);
  k[i] = f2bf(wk[i]);
  o[i] = f2bf(wo[i]);
}

// reduce fp16 split-K8 partials; coalesced both-triangle writes via LDS.
__global__ __launch_bounds__(256) void k_reduceG(const ushort_t* __restrict__ Gp,
                                                 ushort_t* __restrict__ Gb) {
  __shared__ ushort_t ldsM[128 * 36];
  int slab = blockIdx.x, tile = blockIdx.y, b = blockIdx.z;
  int tm = (0x1A449000u >> (tile * 3)) & 7;
  int tn = (0x1B4D1688u >> (tile * 3)) & 7;
  int t = threadIdx.x;
  const ushort_t* base = Gp + ((size_t)b * 8) * 262144 +
                         (size_t)(tm * 128) * 512 + tn * 128 + slab * 32;
  ushort_t* gb = Gb + (size_t)b * 262144;
#pragma unroll
  for (int i = 0; i < 4; ++i) {
    int idx = i * 256 + t;
    int r = idx >> 3, lq = idx & 7;
    const ushort_t* p = base + (size_t)r * 512 + lq * 4;
    float fs[4] = {0.f, 0.f, 0.f, 0.f};
#pragma unroll
    for (int sp = 0; sp < 8; ++sp) {
      us4 a = *reinterpret_cast<const us4*>(p + (size_t)sp * 262144);
#pragma unroll
      for (int j = 0; j < 4; ++j) fs[j] += h2f(a[j]);
    }
    us4 u = {f2bf(fs[0]), f2bf(fs[1]), f2bf(fs[2]), f2bf(fs[3])};
    *reinterpret_cast<us4*>(
        &gb[(size_t)(tm * 128 + r) * 512 + tn * 128 + slab * 32 + lq * 4]) = u;
    if (tm != tn) *reinterpret_cast<us4*>(&ldsM[r * 36 + lq * 4]) = u;
  }
  if (tm == tn) return;
  __syncthreads();
  int orow = t >> 3, og = t & 7;
  ushort_t* dst = &gb[(size_t)(tn * 128 + slab * 32 + orow) * 512 + tm * 128 + og * 16];
#pragma unroll
  for (int h = 0; h < 2; ++h) {
    us8 o;
#pragma unroll
    for (int j = 0; j < 8; ++j) o[j] = ldsM[(og * 16 + h * 8 + j) * 36 + orow];
    *reinterpret_cast<us8*>(dst + h * 8) = o;
  }
}

// u = Wq_n s_b, w = Wk_n s_b  per (b,n); coalesced float4 dots
__global__ __launch_bounds__(256) void k_uw(
    const float* __restrict__ wq, const float* __restrict__ wk,
    const float* __restrict__ s, float* __restrict__ U, float* __restrict__ W) {
  int b = blockIdx.x >> 3, n = blockIdx.x & 7;
  int t = threadIdx.x;
  __shared__ float ssh[NC];
  for (int i = t; i < NC; i += 256) ssh[i] = s[b * NC + i];
  __syncthreads();
  int pair = t >> 1, half = t & 1;
  int d = pair & 63, sel = pair >> 6;
  const float* row = (sel ? wk : wq) + (size_t)(n * DH + d) * NC + half * 256;
  const float* sb = ssh + half * 256;
  float a = 0.f;
#pragma unroll 8
  for (int i = 0; i < 64; ++i) {
    float4 v = reinterpret_cast<const float4*>(row)[i];
    a += v.x * sb[i * 4] + v.y * sb[i * 4 + 1] + v.z * sb[i * 4 + 2] +
         v.w * sb[i * 4 + 3];
  }
  a += __shfl_xor(a, 1, 64);
  if (half == 0) (sel ? W : U)[b * NC + n * DH + d] = a;
}

// per (b,n,half): logits (MFMA, split-bf16 T) -> softmax -> half of M rows.
__global__ __launch_bounds__(256) void k_fused(
    const ushort_t* __restrict__ Thi, const ushort_t* __restrict__ Tlo,
    const ushort_t* __restrict__ Wkb, const ushort_t* __restrict__ Wob,
    const float* __restrict__ U, const float* __restrict__ Wv,
    const float* __restrict__ bq, const float* __restrict__ bk,
    ushort_t* __restrict__ Mb) {
  __shared__ __align__(128) ushort_t Th[64 * 64];
  __shared__ __align__(128) ushort_t Tl[64 * 64];
  __shared__ __align__(128) ushort_t Wks[64 * 64];
  __shared__ float Ps[64][65];
  __shared__ __align__(16) ushort_t PT[64 * 72];
  __shared__ __align__(128) ushort_t Wos[128 * 64];
  __shared__ float ush[64], wsh[64], bqs[64], bks[64];

  int b = blockIdx.x >> 4, n = (blockIdx.x >> 1) & 7, half = blockIdx.x & 1;
  int t = threadIdx.x, lane = t & 63, w = t >> 6;
  int l15 = lane & 15, l4 = lane >> 4;

  if (t < 64) ush[t] = U[b * NC + n * DH + t];
  else if (t < 128) wsh[t - 64] = Wv[b * NC + n * DH + (t - 64)];
  else if (t < 192) bqs[t - 128] = bq[n * DH + (t - 128)];
  else bks[t - 192] = bk[n * DH + (t - 192)];

  const size_t tbase = ((size_t)b * NC + n * DH) * NC;
  f32x4 zero = {0.f, 0.f, 0.f, 0.f};
  f32x4 acc[4];
#pragma unroll
  for (int i = 0; i < 4; ++i) acc[i] = zero;

  for (int kc0 = 0; kc0 < NC; kc0 += 64) {
    __syncthreads();
#pragma unroll
    for (int i = 0; i < 6; ++i) {
      int slab = w * 6 + i;
      int mat = slab >> 3, sl = slab & 7;
      int r = sl * 8 + (lane >> 3);
      int kc = (lane & 7) ^ (r & 7);
      if (mat == 0)
        gld_lds16(Thi + tbase + (size_t)r * NC + kc0 + kc * 8, &Th[sl * 512]);
      else if (mat == 1)
        gld_lds16(Tlo + tbase + (size_t)r * NC + kc0 + kc * 8, &Tl[sl * 512]);
      else
        gld_lds16(Wkb + (size_t)(n * DH + r) * NC + kc0 + kc * 8, &Wks[sl * 512]);
    }
    __syncthreads();
#pragma unroll
    for (int kf = 0; kf < 2; ++kf) {
      int rn = w * 16 + l15;
      int cn = (kf * 4 + l4) ^ (rn & 7);
      bf16x8 bvf = *(const bf16x8*)&Wks[rn * 64 + cn * 8];
#pragma unroll
      for (int i = 0; i < 4; ++i) {
        int r = i * 16 + l15;
        int c = (kf * 4 + l4) ^ (r & 7);
        bf16x8 ah = *(const bf16x8*)&Th[r * 64 + c * 8];
        bf16x8 al = *(const bf16x8*)&Tl[r * 64 + c * 8];
        acc[i] = __builtin_amdgcn_mfma_f32_16x16x32_bf16(ah, bvf, acc[i], 0, 0, 0);
        acc[i] = __builtin_amdgcn_mfma_f32_16x16x32_bf16(al, bvf, acc[i], 0, 0, 0);
      }
    }
  }
#pragma unroll
  for (int i = 0; i < 4; ++i)
#pragma unroll
    for (int rr = 0; rr < 4; ++rr) {
      int d = i * 16 + l4 * 4 + rr, e = w * 16 + l15;
      float v = acc[i][rr] + ush[d] * bks[e] + bqs[d] * (wsh[e] + 4096.f * bks[e]);
      Ps[d][e] = v * 0.125f;
    }
  __syncthreads();
  {
    int d = w * 16 + l15;
    float mx = -1e30f;
#pragma unroll
    for (int i = 0; i < 16; ++i) mx = fmaxf(mx, Ps[d][l4 * 16 + i]);
    mx = fmaxf(mx, __shfl_xor(mx, 16, 64));
    mx = fmaxf(mx, __shfl_xor(mx, 32, 64));
    float pv[16];
    float sum = 0.f;
#pragma unroll
    for (int i = 0; i < 16; ++i) {
      pv[i] = __expf(Ps[d][l4 * 16 + i] - mx);
      sum += pv[i];
    }
    sum += __shfl_xor(sum, 16, 64);
    sum += __shfl_xor(sum, 32, 64);
    float inv = 1.f / sum;
#pragma unroll
    for (int i = 0; i < 16; ++i) PT[(l4 * 16 + i) * 72 + d] = f2bf(pv[i] * inv);
  }
  for (int mi = 0; mi < 2; ++mi) {
    int mt = half * 2 + mi;
    __syncthreads();
#pragma unroll
    for (int i = 0; i < 4; ++i) {
      int slab = w * 4 + i;
      int r = slab * 8 + (lane >> 3);
      int kc = (lane & 7) ^ (r & 7);
      gld_lds16(Wob + (size_t)(mt * 128 + r) * NC + n * DH + kc * 8,
                &Wos[slab * 512]);
    }
    __syncthreads();
    f32x4 acc2[2][4];
#pragma unroll
    for (int i2 = 0; i2 < 2; ++i2)
#pragma unroll
      for (int j = 0; j < 4; ++j) acc2[i2][j] = zero;
#pragma unroll
    for (int kf = 0; kf < 2; ++kf) {
      bf16x8 bv[4];
#pragma unroll
      for (int j = 0; j < 4; ++j) {
        int e = j * 16 + l15;
        bv[j] = *(const bf16x8*)&PT[e * 72 + (kf * 4 + l4) * 8];
      }
#pragma unroll
      for (int i2 = 0; i2 < 2; ++i2) {
        int r = w * 32 + i2 * 16 + l15;
        int c = (kf * 4 + l4) ^ (r & 7);
        bf16x8 av = *(const bf16x8*)&Wos[r * 64 + c * 8];
#pragma unroll
        for (int j = 0; j < 4; ++j)
          acc2[i2][j] =
              __builtin_amdgcn_mfma_f32_16x16x32_bf16(av, bv[j], acc2[i2][j], 0, 0, 0);
      }
    }
#pragma unroll
    for (int i2 = 0; i2 < 2; ++i2)
#pragma unroll
      for (int j = 0; j < 4; ++j)
#pragma unroll
        for (int rr = 0; rr < 4; ++rr) {
          int grow = mt * 128 + w * 32 + i2 * 16 + l4 * 4 + rr;
          int gcol = n * DH + j * 16 + l15;
          float v = acc2[i2][j][rr];
          if (grow == gcol) v += 1.f;  // fold residual
          Mb[((size_t)b * NC + grow) * NC + gcol] = f2bf(v);
        }
  }
}

// ---------------- fallback fp32 vector path (round-1, known-good) -----------
#define BKt 32
#define BMt 128
#define BNt 128
#define LDTK 132

__global__ __launch_bounds__(256) void k_rowsum(const float* __restrict__ x,
                                                float* __restrict__ s) {
  int row = blockIdx.x;
  const float* xr = x + (size_t)row * NP;
  int t = threadIdx.x;
  float acc = 0.f;
  for (int i = t; i < NP / 4; i += 256) {
    float4 v = reinterpret_cast<const float4*>(xr)[i];
    acc += (v.x + v.y) + (v.z + v.w);
  }
  for (int off = 32; off > 0; off >>= 1) acc += __shfl_down(acc, off, 64);
  __shared__ float red[4];
  int lane = t & 63, wv = t >> 6;
  if (lane == 0) red[wv] = acc;
  __syncthreads();
  if (t == 0) s[row] = (red[0] + red[1]) + (red[2] + red[3]);
}

__global__ __launch_bounds__(256) void k_gemm_abT(
    const float* __restrict__ Abase, const float* __restrict__ Bbase,
    float* __restrict__ Cbase, int K, int lda, int ldb, int ldc,
    size_t sA, size_t sB, size_t sC) {
  __shared__ float As[BKt][LDTK];
  __shared__ float Bs[BKt][LDTK];
  const float* A = Abase + sA * blockIdx.z;
  const float* Bm = Bbase + sB * blockIdx.z;
  float* Cm = Cbase + sC * blockIdx.z;
  int m0 = blockIdx.y * BMt, n0 = blockIdx.x * BNt;
  int t = threadIdx.x;
  int tr = t >> 4, tc = t & 15;
  float acc[8][8];
#pragma unroll
  for (int i = 0; i < 8; ++i)
#pragma unroll
    for (int j = 0; j < 8; ++j) acc[i][j] = 0.f;
  for (int k0 = 0; k0 < K; k0 += BKt) {
#pragma unroll
    for (int it = 0; it < 4; ++it) {
      int idx = it * 256 + t;
      int r = idx >> 3, kq = idx & 7;
      float4 va = *reinterpret_cast<const float4*>(A + (size_t)(m0 + r) * lda + k0 + kq * 4);
      As[kq * 4 + 0][r] = va.x; As[kq * 4 + 1][r] = va.y;
      As[kq * 4 + 2][r] = va.z; As[kq * 4 + 3][r] = va.w;
      float4 vb = *reinterpret_cast<const float4*>(Bm + (size_t)(n0 + r) * ldb + k0 + kq * 4);
      Bs[kq * 4 + 0][r] = vb.x; Bs[kq * 4 + 1][r] = vb.y;
      Bs[kq * 4 + 2][r] = vb.z; Bs[kq * 4 + 3][r] = vb.w;
    }
    __syncthreads();
#pragma unroll
    for (int kk = 0; kk < BKt; ++kk) {
      float4 a0 = *reinterpret_cast<const float4*>(&As[kk][tr * 8]);
      float4 a1 = *reinterpret_cast<const float4*>(&As[kk][tr * 8 + 4]);
      float4 b0 = *reinterpret_cast<const float4*>(&Bs[kk][tc * 8]);
      float4 b1 = *reinterpret_cast<const float4*>(&Bs[kk][tc * 8 + 4]);
      float av[8] = {a0.x, a0.y, a0.z, a0.w, a1.x, a1.y, a1.z, a1.w};
      float bv[8] = {b0.x, b0.y, b0.z, b0.w, b1.x, b1.y, b1.z, b1.w};
#pragma unroll
      for (int i = 0; i < 8; ++i)
#pragma unroll
        for (int j = 0; j < 8; ++j) acc[i][j] += av[i] * bv[j];
    }
    __syncthreads();
  }
#pragma unroll
  for (int i = 0; i < 8; ++i) {
    float* crow = Cm + (size_t)(m0 + tr * 8 + i) * ldc + n0 + tc * 8;
    float4 c0 = {acc[i][0], acc[i][1], acc[i][2], acc[i][3]};
    float4 c1 = {acc[i][4], acc[i][5], acc[i][6], acc[i][7]};
    *reinterpret_cast<float4*>(crow) = c0;
    *reinterpret_cast<float4*>(crow + 4) = c1;
  }
}

__global__ __launch_bounds__(256) void k_gemm_ab(
    const float* __restrict__ Abase, const float* __restrict__ Bbase,
    float* __restrict__ Cbase, const float* __restrict__ bias,
    int K, int lda, int ldb, int ldc, size_t sA, size_t sB, size_t sC) {
  __shared__ float As[BKt][LDTK];
  __shared__ float Bs[BKt][LDTK];
  const float* A = Abase + sA * blockIdx.z;
  const float* Bm = Bbase + sB * blockIdx.z;
  float* Cm = Cbase + sC * blockIdx.z;
  int m0 = blockIdx.y * BMt, n0 = blockIdx.x * BNt;
  int t = threadIdx.x;
  int tr = t >> 4, tc = t & 15;
  float acc[8][8];
#pragma unroll
  for (int i = 0; i < 8; ++i)
#pragma unroll
    for (int j = 0; j < 8; ++j) acc[i][j] = 0.f;
  for (int k0 = 0; k0 < K; k0 += BKt) {
#pragma unroll
    for (int it = 0; it < 4; ++it) {
      int idx = it * 256 + t;
      int r = idx >> 3, kq = idx & 7;
      float4 va = *reinterpret_cast<const float4*>(A + (size_t)(m0 + r) * lda + k0 + kq * 4);
      As[kq * 4 + 0][r] = va.x; As[kq * 4 + 1][r] = va.y;
      As[kq * 4 + 2][r] = va.z; As[kq * 4 + 3][r] = va.w;
      int kk = idx >> 5, nq = idx & 31;
      float4 vb = *reinterpret_cast<const float4*>(Bm + (size_t)(k0 + kk) * ldb + n0 + nq * 4);
      *reinterpret_cast<float4*>(&Bs[kk][nq * 4]) = vb;
    }
    __syncthreads();
#pragma unroll
    for (int kk = 0; kk < BKt; ++kk) {
      float4 a0 = *reinterpret_cast<const float4*>(&As[kk][tr * 8]);
      float4 a1 = *reinterpret_cast<const float4*>(&As[kk][tr * 8 + 4]);
      float4 b0 = *reinterpret_cast<const float4*>(&Bs[kk][tc * 8]);
      float4 b1 = *reinterpret_cast<const float4*>(&Bs[kk][tc * 8 + 4]);
      float av[8] = {a0.x, a0.y, a0.z, a0.w, a1.x, a1.y, a1.z, a1.w};
      float bv[8] = {b0.x, b0.y, b0.z, b0.w, b1.x, b1.y, b1.z, b1.w};
#pragma unroll
      for (int i = 0; i < 8; ++i)
#pragma unroll
        for (int j = 0; j < 8; ++j) acc[i][j] += av[i] * bv[j];
    }
    __syncthreads();
  }
#pragma unroll
  for (int i = 0; i < 8; ++i) {
    int row = m0 + tr * 8 + i;
    float bb = bias ? bias[row] : 0.f;
    float* crow = Cm + (size_t)row * ldc + n0 + tc * 8;
    float4 c0 = {acc[i][0] + bb, acc[i][1] + bb, acc[i][2] + bb, acc[i][3] + bb};
    float4 c1 = {acc[i][4] + bb, acc[i][5] + bb, acc[i][6] + bb, acc[i][7] + bb};
    *reinterpret_cast<float4*>(crow) = c0;
    *reinterpret_cast<float4*>(crow + 4) = c1;
  }
}

__global__ __launch_bounds__(256) void k_att(
    const float* __restrict__ T, const float* __restrict__ wq,
    const float* __restrict__ bq, const float* __restrict__ wk,
    const float* __restrict__ bk, const float* __restrict__ wo,
    const float* __restrict__ s, float* __restrict__ Mf) {
  int b = blockIdx.x >> 3, n = blockIdx.x & 7;
  int t = threadIdx.x;
  __shared__ float sh_s[NC];
  __shared__ float sh_u[DH], sh_w[DH];
  __shared__ float L[DH][DH + 1];
  __shared__ float Ts[DH][68];
  __shared__ float Ks[DH][68];

  for (int i = t; i < NC; i += 256) sh_s[i] = s[b * NC + i];
  __syncthreads();
  if (t < 128) {
    int d = t & 63;
    const float* wrow = (t < 64 ? wq : wk) + (size_t)(n * DH + d) * NC;
    float a = 0.f;
    for (int c = 0; c < NC; ++c) a += wrow[c] * sh_s[c];
    if (t < 64) sh_u[d] = a; else sh_w[d] = a;
  }

  int d = t >> 2, eg = t & 3;
  float acc[16];
#pragma unroll
  for (int i = 0; i < 16; ++i) acc[i] = 0.f;

  for (int c0 = 0; c0 < NC; c0 += 64) {
#pragma unroll
    for (int it = 0; it < 4; ++it) {
      int idx = it * 256 + t;
      int r = idx >> 4, cq = idx & 15;
      float4 v = *reinterpret_cast<const float4*>(
          T + ((size_t)b * NC + n * DH + r) * NC + c0 + cq * 4);
      *reinterpret_cast<float4*>(&Ts[r][cq * 4]) = v;
      float4 kv = *reinterpret_cast<const float4*>(
          wk + (size_t)(n * DH + r) * NC + c0 + cq * 4);
      Ks[cq * 4 + 0][r] = kv.x; Ks[cq * 4 + 1][r] = kv.y;
      Ks[cq * 4 + 2][r] = kv.z; Ks[cq * 4 + 3][r] = kv.w;
    }
    __syncthreads();
    for (int cc = 0; cc < 64; ++cc) {
      float tv = Ts[d][cc];
      float4 k0v = *reinterpret_cast<const float4*>(&Ks[cc][eg * 16]);
      float4 k1v = *reinterpret_cast<const float4*>(&Ks[cc][eg * 16 + 4]);
      float4 k2v = *reinterpret_cast<const float4*>(&Ks[cc][eg * 16 + 8]);
      float4 k3v = *reinterpret_cast<const float4*>(&Ks[cc][eg * 16 + 12]);
      acc[0] += tv * k0v.x;  acc[1] += tv * k0v.y;
      acc[2] += tv * k0v.z;  acc[3] += tv * k0v.w;
      acc[4] += tv * k1v.x;  acc[5] += tv * k1v.y;
      acc[6] += tv * k1v.z;  acc[7] += tv * k1v.w;
      acc[8] += tv * k2v.x;  acc[9] += tv * k2v.y;
      acc[10] += tv * k2v.z; acc[11] += tv * k2v.w;
      acc[12] += tv * k3v.x; acc[13] += tv * k3v.y;
      acc[14] += tv * k3v.z; acc[15] += tv * k3v.w;
    }
    __syncthreads();
  }

  float bqd = bq[n * DH + d];
  float ud = sh_u[d];
#pragma unroll
  for (int i = 0; i < 16; ++i) {
    int e = eg * 16 + i;
    float bke = bk[n * DH + e];
    L[d][e] = (acc[i] + ud * bke + bqd * (sh_w[e] + (float)NP * bke)) * 0.125f;
  }
  __syncthreads();
  if (t < 64) {
    float mx = -1e30f;
    for (int e = 0; e < DH; ++e) mx = fmaxf(mx, L[t][e]);
    float sum = 0.f;
    for (int e = 0; e < DH; ++e) { float p = __expf(L[t][e] - mx); L[t][e] = p; sum += p; }
    float inv = 1.f / sum;
    for (int e = 0; e < DH; ++e) L[t][e] *= inv;
  }
  __syncthreads();

#pragma unroll
  for (int rep = 0; rep < 2; ++rep) {
    int o = rep * 256 + t;
    const float* worow = wo + (size_t)o * NC + n * DH;
    float wreg[64];
#pragma unroll
    for (int q = 0; q < 16; ++q) {
      float4 v = *reinterpret_cast<const float4*>(worow + q * 4);
      wreg[q * 4 + 0] = v.x; wreg[q * 4 + 1] = v.y;
      wreg[q * 4 + 2] = v.z; wreg[q * 4 + 3] = v.w;
    }
    for (int e = 0; e < DH; ++e) {
      float a = 0.f;
#pragma unroll
      for (int dd = 0; dd < DH; ++dd) a += wreg[dd] * L[dd][e];
      int col = n * DH + e;
      if (o == col) a += 1.f;
      Mf[((size_t)b * NC + o) * NC + col] = a;
    }
  }
}

extern "C" void kernel_launch(void* const* d_in, const int* in_sizes, int n_in,
                              void* d_out, int out_size, void* d_ws, size_t ws_size,
                              hipStream_t stream) {
  const float* x  = (const float*)d_in[0];
  const float* wq = (const float*)d_in[1];
  const float* bq = (const float*)d_in[2];
  const float* wk = (const float*)d_in[3];
  const float* bk = (const float*)d_in[4];
  const float* wo = (const float*)d_in[5];
  const float* bo = (const float*)d_in[6];
  float* out = (float*)d_out;
  char* ws = (char*)d_ws;

  const size_t sX = (size_t)NC * NP;  // 2097152
  const size_t sG = (size_t)NC * NC;  // 262144
  const size_t xbf_bytes = (size_t)NB * sX * 2;  // 64 MiB

  size_t off_s  = 0;                                   // 32 KiB
  size_t off_sp = 32768;                               // sPart: 2 MiB
  size_t off_xt = off_sp + (size_t)64 * NB * NC * 4;   // 64 MiB (tiled)
  size_t off_mb = off_xt + xbf_bytes;                  // 8 MiB
  size_t off_wq = off_mb + (size_t)NB * sG * 2;
  size_t off_wk = off_wq + sG * 2;
  size_t off_wo = off_wk + sG * 2;
  size_t off_u  = off_wo + sG * 2;
  size_t off_w  = off_u + 32768;
  size_t need   = off_w + 32768;

  if (ws_size >= need + 4096) {
    // ---- fast MFMA path ----
    float*    s     = (float*)(ws + off_s);
    float*    sPart = (float*)(ws + off_sp);
    ushort_t* Xt    = (ushort_t*)(ws + off_xt);
    ushort_t* Mb    = (ushort_t*)(ws + off_mb);
    ushort_t* Wqb   = (ushort_t*)(ws + off_wq);
    ushort_t* Wkb   = (ushort_t*)(ws + off_wk);
    ushort_t* Wob   = (ushort_t*)(ws + off_wo);
    float*    U     = (float*)(ws + off_u);
    float*    W     = (float*)(ws + off_w);
    char* dob = (char*)d_out;
    ushort_t* Xbf   = (ushort_t*)d_out;            // [0,64M): dead after Gram
    ushort_t* Gpart = (ushort_t*)(dob + xbf_bytes); // [64M,128M): fp16 partials x8
    ushort_t* Gb    = (ushort_t*)d_out;            // [0,8M) after Gram
    ushort_t* Thi   = (ushort_t*)(dob + xbf_bytes);     // [64M,72M)
    ushort_t* Tlo   = Thi + 4194304;                    // [72M,80M)

    k_cvtw<<<dim3(1024), 256, 0, stream>>>(wq, wk, wo, Wqb, Wkb, Wob);
    k_prep<<<dim3(64, 8, 16), 256, 0, stream>>>(x, Xbf, Xt, sPart);
    k_sreduce<<<dim3(32), 256, 0, stream>>>(sPart, s);
    k_uw<<<dim3(NB * NHD), 256, 0, stream>>>(wq, wk, s, U, W);
    // triangle Gram split-K=8, fp16 partials
    k_mfma_bt<<<dim3(10, 1, 128), 256, 0, stream>>>(
        Xbf, Xbf, Gpart, nullptr, NP, NP, NC,
        (long long)sX, (long long)sX, (long long)sG, NP / 8, 4, 2);
    k_reduceG<<<dim3(4, 10, 16), 256, 0, stream>>>(Gpart, Gb);
    // T_b = Wq * G_b -> split-bf16 hi/lo (G symmetric -> bt-form valid)
    k_mfma_bt<<<dim3(4, 4, 16), 256, 0, stream>>>(
        Wqb, Gb, Thi, nullptr, NC, NC, NC,
        0LL, (long long)sG, (long long)sG, NC, 3, 1);
    // logits -> softmax -> M' = Wo*blockdiag(P) + I  (bf16), 2 blocks/(b,n)
    k_fused<<<dim3(NB * NHD * 2), 256, 0, stream>>>(Thi, Tlo, Wkb, Wob, U, W,
                                                    bq, bk, Mb);
    // out = (M+I) X + bo  (n-grouped XCD decode + tiled-B + nontemporal stores)
    k_mfma_bt<<<dim3(2048), 256, 0, stream>>>(
        Mb, Xt, out, bo, NC, NC, NP,
        (long long)sG, (long long)sX, (long long)sX, NC, 1, 12);
  } else {
    // ---- fallback: round-1 fp32 vector path ----
    float* s  = (float*)ws;
    float* G  = (float*)(ws + 32768);
    float* Tm = (float*)(ws + 32768 + (size_t)NB * sG * 4);
    float* M  = G;
    k_rowsum<<<NB * NC, 256, 0, stream>>>(x, s);
    k_gemm_abT<<<dim3(4, 4, NB), 256, 0, stream>>>(x, x, G, NP, NP, NP, NC, sX, sX, sG);
    k_gemm_ab<<<dim3(4, 4, NB), 256, 0, stream>>>(wq, G, Tm, nullptr, NC, NC, NC, NC,
                                                  0, sG, sG);
    k_att<<<NB * NHD, 256, 0, stream>>>(Tm, wq, bq, wk, bk, wo, s, M);
    k_gemm_ab<<<dim3(NP / BNt, NC / BMt, NB), 256, 0, stream>>>(M, x, out, bo, NC, NC,
                                                                NP, NP, sG, sX, sX);
  }
}

// Round 14
// 196.176 us; speedup vs baseline: 1.1355x; 1.1355x over previous
//
#include <hip/hip_runtime.h>

// AttentionModule: B=16, C=512, H=W=64 (P=4096), nh=8, dh=64.
//   G_b = X_b X_b^T ; s_b = X_b 1
//   att_n * 8 = Wq_n G Wk_n^T + (Wq_n s) bk_n^T + bq_n (Wk_n s)^T + P bq_n bk_n^T
//   P_n = softmax_rows(att_n) ; M[:, nblk] = Wo_n P_n ; out = (M+I) X + bo
// R14: strict revert to R12 (best-known ~200us). R13's two changes both
//      regressed (NT prep stores: null; Gram split-K8: +20us traffic).

typedef unsigned short ushort_t;
typedef __attribute__((ext_vector_type(8))) short bf16x8;
typedef __attribute__((ext_vector_type(4))) float f32x4;
typedef __attribute__((ext_vector_type(4))) unsigned short us4;
typedef __attribute__((ext_vector_type(8))) unsigned short us8;

#define NB 16
#define NC 512
#define NP 4096
#define NHD 8
#define DH 64

#define BM 128
#define BN 128
#define BKK 64

__device__ inline ushort_t f2bf(float f) {
  unsigned int u = __float_as_uint(f);
  u += 0x7FFFu + ((u >> 16) & 1u);
  return (ushort_t)(u >> 16);
}
__device__ inline float bf2f(ushort_t h) {
  return __uint_as_float(((unsigned int)h) << 16);
}
__device__ inline ushort_t f2h(float f) {
  _Float16 h = (_Float16)f;
  return *(ushort_t*)&h;
}
__device__ inline float h2f(ushort_t u) {
  _Float16 h;
  *(ushort_t*)&h = u;
  return (float)h;
}

__device__ inline void gld_lds16(const void* g, void* l) {
  __builtin_amdgcn_global_load_lds(
      (const __attribute__((address_space(1))) unsigned int*)g,
      (__attribute__((address_space(3))) unsigned int*)l, 16, 0, 0);
}

// ---------------- MFMA bt-GEMM: C[m,n] = sum_k A[m,k]*B[n,k] ----------------
// mode 1: C fp32 + bias[row], scalar NONTEMPORAL stores.
// mode 2: C fp32. mode 3: C split-bf16 hi/lo (lo at +4194304 elements).
// mode 4: C fp16 (Gram partials).
// flags bit0: XCD swizzle within z. bit1: triangle split-K4 Gram (grid x=10,z=64).
// bit2: final-GEMM decode (1-D grid 2048, XCD-chunked, n-groups of 16).
// bit3: B operand is [n/128][k/64][128][64]-tiled (8192 elems/tile).
__global__ __launch_bounds__(256, 4) void k_mfma_bt(
    const ushort_t* __restrict__ A, const ushort_t* __restrict__ B,
    void* __restrict__ Cv, const float* __restrict__ bias,
    int lda, int ldb, int ldc, long long sA, long long sB, long long sC,
    int Kper, int mode, int flags) {
  __shared__ __align__(128) ushort_t As[BM * BKK];
  __shared__ __align__(128) ushort_t Bs[BN * BKK];
  int m0, n0;
  long long zc;
  const ushort_t *Ab, *Bb;
  if (flags & 4) {
    int id = blockIdx.x;                               // 2048 blocks
    int nf = (id & 7) * 256 + (id >> 3);               // XCD-chunked bijection
    int z = nf >> 7;                                   // batch (2 per XCD)
    int r = nf & 127;
    int ng = r >> 6;                                   // n-group of 16
    int m = (r >> 4) & 3;
    int nn = ng * 16 + (r & 15);                       // n fastest within group
    m0 = m * BM; n0 = nn * BN;
    Ab = A + z * sA; Bb = B + z * sB;
    zc = (long long)z * sC;
  } else if (flags & 2) {
    int flat = blockIdx.x + 10 * blockIdx.z;          // 640 blocks
    int nf = (flat & 7) * 80 + (flat >> 3);           // XCD-chunked bijection
    int z2 = nf / 10, tile = nf - z2 * 10;
    int bb = z2 >> 2, sp = z2 & 3;
    int tm = (0x1A449000u >> (tile * 3)) & 7;         // {0,0,0,0,1,1,1,2,2,3}
    int tn = (0x1B4D1688u >> (tile * 3)) & 7;         // {0,1,2,3,1,2,3,2,3,3}
    m0 = tm * BM; n0 = tn * BN;
    Ab = A + bb * sA + (long long)sp * Kper;
    Bb = B + bb * sB + (long long)sp * Kper;
    zc = (long long)z2 * sC;
  } else {
    int bx = blockIdx.x, by = blockIdx.y;
    if (flags & 1) {
      int nxy = gridDim.x * gridDim.y;
      int id = bx + gridDim.x * by;
      int nid = (id & 7) * (nxy >> 3) + (id >> 3);
      bx = nid % gridDim.x; by = nid / gridDim.x;
    }
    m0 = by * BM; n0 = bx * BN;
    Ab = A + blockIdx.z * sA;
    Bb = B + blockIdx.z * sB;
    zc = (long long)blockIdx.z * sC;
  }
  int t = threadIdx.x;
  int lane = t & 63, w = t >> 6;
  int wr = w >> 1, wc = w & 1;
  int l15 = lane & 15, l4 = lane >> 4;
  int sr = lane >> 3, scc = lane & 7;

  f32x4 zero = {0.f, 0.f, 0.f, 0.f};
  f32x4 acc[4][4];
#pragma unroll
  for (int i = 0; i < 4; ++i)
#pragma unroll
    for (int j = 0; j < 4; ++j) acc[i][j] = zero;

  for (int k0 = 0; k0 < Kper; k0 += BKK) {
#pragma unroll
    for (int i = 0; i < 4; ++i) {
      int slab = w * 4 + i;
      int r = slab * 8 + sr;
      int kc = scc ^ (r & 7);   // pre-swizzled source chunk (involution)
      gld_lds16(Ab + (size_t)(m0 + r) * lda + k0 + kc * 8, &As[slab * 512]);
      if (flags & 8) {
        gld_lds16(Bb + ((size_t)((n0 >> 7) * 8 + (k0 >> 6))) * 8192 + r * 64 + kc * 8,
                  &Bs[slab * 512]);
      } else {
        gld_lds16(Bb + (size_t)(n0 + r) * ldb + k0 + kc * 8, &Bs[slab * 512]);
      }
    }
    __syncthreads();
#pragma unroll
    for (int kf = 0; kf < 2; ++kf) {
      bf16x8 av[4], bv[4];
#pragma unroll
      for (int i = 0; i < 4; ++i) {
        int r = wr * 64 + i * 16 + l15;
        int c = (kf * 4 + l4) ^ (r & 7);
        av[i] = *(const bf16x8*)&As[r * 64 + c * 8];
        int rn = wc * 64 + i * 16 + l15;
        int cn = (kf * 4 + l4) ^ (rn & 7);
        bv[i] = *(const bf16x8*)&Bs[rn * 64 + cn * 8];
      }
#pragma unroll
      for (int i = 0; i < 4; ++i)
#pragma unroll
        for (int j = 0; j < 4; ++j)
          acc[i][j] = __builtin_amdgcn_mfma_f32_16x16x32_bf16(av[i], bv[j],
                                                              acc[i][j], 0, 0, 0);
    }
    __syncthreads();
  }

  if (mode == 3) {
    ushort_t* C = (ushort_t*)Cv + zc;
#pragma unroll
    for (int i = 0; i < 4; ++i)
#pragma unroll
      for (int j = 0; j < 4; ++j)
#pragma unroll
        for (int rr = 0; rr < 4; ++rr) {
          int grow = m0 + wr * 64 + i * 16 + l4 * 4 + rr;
          int gcol = n0 + wc * 64 + j * 16 + l15;
          float v = acc[i][j][rr];
          ushort_t hi = f2bf(v);
          C[(size_t)grow * ldc + gcol] = hi;
          C[4194304 + (size_t)grow * ldc + gcol] = f2bf(v - bf2f(hi));
        }
  } else if (mode == 4) {
    ushort_t* C = (ushort_t*)Cv + zc;
#pragma unroll
    for (int i = 0; i < 4; ++i)
#pragma unroll
      for (int j = 0; j < 4; ++j)
#pragma unroll
        for (int rr = 0; rr < 4; ++rr) {
          int grow = m0 + wr * 64 + i * 16 + l4 * 4 + rr;
          int gcol = n0 + wc * 64 + j * 16 + l15;
          C[(size_t)grow * ldc + gcol] = f2h(acc[i][j][rr]);
        }
  } else if (mode == 1) {
    float* C = (float*)Cv + zc;
#pragma unroll
    for (int i = 0; i < 4; ++i)
#pragma unroll
      for (int j = 0; j < 4; ++j)
#pragma unroll
        for (int rr = 0; rr < 4; ++rr) {
          int grow = m0 + wr * 64 + i * 16 + l4 * 4 + rr;
          int gcol = n0 + wc * 64 + j * 16 + l15;
          __builtin_nontemporal_store(acc[i][j][rr] + bias[grow],
                                      &C[(size_t)grow * ldc + gcol]);
        }
  } else {
    float* C = (float*)Cv + zc;
#pragma unroll
    for (int i = 0; i < 4; ++i)
#pragma unroll
      for (int j = 0; j < 4; ++j)
#pragma unroll
        for (int rr = 0; rr < 4; ++rr) {
          int grow = m0 + wr * 64 + i * 16 + l4 * 4 + rr;
          int gcol = n0 + wc * 64 + j * 16 + l15;
          C[(size_t)grow * ldc + gcol] = acc[i][j][rr];
        }
  }
}

// ------- prep: X fp32 -> Xbf [c][p], Xt TILED (bf16), partial row sums -----
__global__ __launch_bounds__(256) void k_prep(const float* __restrict__ x,
                                              ushort_t* __restrict__ xbf,
                                              ushort_t* __restrict__ xt,
                                              float* __restrict__ sPart) {
  __shared__ float tile[64][65];
  int b = blockIdx.z;
  const float* xb = x + (size_t)b * NC * NP;
  int t = threadIdx.x;
  int pp0 = blockIdx.x * 64, cc0 = blockIdx.y * 64;
#pragma unroll
  for (int i = 0; i < 4; ++i) {
    int idx = i * 256 + t;
    int r = idx >> 4, q = idx & 15;
    float4 v = *reinterpret_cast<const float4*>(
        xb + (size_t)(cc0 + r) * NP + pp0 + q * 4);
    us4 u = {f2bf(v.x), f2bf(v.y), f2bf(v.z), f2bf(v.w)};
    *reinterpret_cast<us4*>(
        &xbf[((size_t)b * NC + cc0 + r) * NP + pp0 + q * 4]) = u;
    tile[r][q * 4 + 0] = v.x; tile[r][q * 4 + 1] = v.y;
    tile[r][q * 4 + 2] = v.z; tile[r][q * 4 + 3] = v.w;
  }
  __syncthreads();
  {
    int r = t >> 2, q = t & 3;
    float ps = 0.f;
#pragma unroll
    for (int i = 0; i < 16; ++i) ps += tile[r][q * 16 + i];
    ps += __shfl_down(ps, 1, 64);
    ps += __shfl_down(ps, 2, 64);
    if (q == 0)
      sPart[(size_t)blockIdx.x * (NB * NC) + b * NC + cc0 + r] = ps;
  }
  {
    int p = t >> 2, cg = t & 3;
    us8 lo, hi;
#pragma unroll
    for (int i = 0; i < 8; ++i) lo[i] = f2bf(tile[cg * 16 + i][p]);
#pragma unroll
    for (int i = 0; i < 8; ++i) hi[i] = f2bf(tile[cg * 16 + 8 + i][p]);
    int prow = ((blockIdx.x & 1) << 6) + p;  // row within the 128-row tile
    ushort_t* dst =
        &xt[((((size_t)b * 32 + (blockIdx.x >> 1)) * 8 + blockIdx.y)) * 8192 +
            (size_t)prow * 64 + cg * 16];
    *reinterpret_cast<us8*>(dst) = lo;
    *reinterpret_cast<us8*>(dst + 8) = hi;
  }
}

__global__ __launch_bounds__(256) void k_sreduce(const float* __restrict__ sPart,
                                                 float* __restrict__ s) {
  int idx = blockIdx.x * 256 + threadIdx.x;
  float a = 0.f;
  for (int pb = 0; pb < 64; ++pb) a += sPart[(size_t)pb * (NB * NC) + idx];
  s[idx] = a;
}

__global__ __launch_bounds__(256) void k_cvtw(
    const float* __restrict__ wq, const float* __restrict__ wk,
    const float* __restrict__ wo, ushort_t* __restrict__ q,
    ushort_t* __restrict__ k, ushort_t* __restrict__ o) {
  int i = blockIdx.x * 256 + threadIdx.x;
  q[i] = f2bf(wq[i]);
  k[i] = f2bf(wk[i]);
  o[i] = f2bf(wo[i]);
}

// reduce fp16 split-K partials; coalesced both-triangle writes via LDS transpose.
__global__ __launch_bounds__(256) void k_reduceG(const ushort_t* __restrict__ Gp,
                                                 ushort_t* __restrict__ Gb) {
  __shared__ ushort_t ldsM[128 * 36];
  int slab = blockIdx.x, tile = blockIdx.y, b = blockIdx.z;
  int tm = (0x1A449000u >> (tile * 3)) & 7;
  int tn = (0x1B4D1688u >> (tile * 3)) & 7;
  int t = threadIdx.x;
  const ushort_t* base = Gp + ((size_t)b * 4) * 262144 +
                         (size_t)(tm * 128) * 512 + tn * 128 + slab * 32;
  ushort_t* gb = Gb + (size_t)b * 262144;
#pragma unroll
  for (int i = 0; i < 4; ++i) {
    int idx = i * 256 + t;
    int r = idx >> 3, lq = idx & 7;
    const ushort_t* p = base + (size_t)r * 512 + lq * 4;
    us4 a0 = *reinterpret_cast<const us4*>(p);
    us4 a1 = *reinterpret_cast<const us4*>(p + 262144);
    us4 a2 = *reinterpret_cast<const us4*>(p + 2 * 262144);
    us4 a3 = *reinterpret_cast<const us4*>(p + 3 * 262144);
    us4 u;
#pragma unroll
    for (int j = 0; j < 4; ++j)
      u[j] = f2bf((h2f(a0[j]) + h2f(a1[j])) + (h2f(a2[j]) + h2f(a3[j])));
    *reinterpret_cast<us4*>(
        &gb[(size_t)(tm * 128 + r) * 512 + tn * 128 + slab * 32 + lq * 4]) = u;
    if (tm != tn) *reinterpret_cast<us4*>(&ldsM[r * 36 + lq * 4]) = u;
  }
  if (tm == tn) return;
  __syncthreads();
  int orow = t >> 3, og = t & 7;
  ushort_t* dst = &gb[(size_t)(tn * 128 + slab * 32 + orow) * 512 + tm * 128 + og * 16];
#pragma unroll
  for (int h = 0; h < 2; ++h) {
    us8 o;
#pragma unroll
    for (int j = 0; j < 8; ++j) o[j] = ldsM[(og * 16 + h * 8 + j) * 36 + orow];
    *reinterpret_cast<us8*>(dst + h * 8) = o;
  }
}

// u = Wq_n s_b, w = Wk_n s_b  per (b,n); coalesced float4 dots
__global__ __launch_bounds__(256) void k_uw(
    const float* __restrict__ wq, const float* __restrict__ wk,
    const float* __restrict__ s, float* __restrict__ U, float* __restrict__ W) {
  int b = blockIdx.x >> 3, n = blockIdx.x & 7;
  int t = threadIdx.x;
  __shared__ float ssh[NC];
  for (int i = t; i < NC; i += 256) ssh[i] = s[b * NC + i];
  __syncthreads();
  int pair = t >> 1, half = t & 1;
  int d = pair & 63, sel = pair >> 6;
  const float* row = (sel ? wk : wq) + (size_t)(n * DH + d) * NC + half * 256;
  const float* sb = ssh + half * 256;
  float a = 0.f;
#pragma unroll 8
  for (int i = 0; i < 64; ++i) {
    float4 v = reinterpret_cast<const float4*>(row)[i];
    a += v.x * sb[i * 4] + v.y * sb[i * 4 + 1] + v.z * sb[i * 4 + 2] +
         v.w * sb[i * 4 + 3];
  }
  a += __shfl_xor(a, 1, 64);
  if (half == 0) (sel ? W : U)[b * NC + n * DH + d] = a;
}

// per (b,n,half): logits (MFMA, split-bf16 T) -> softmax -> half of M rows.
__global__ __launch_bounds__(256) void k_fused(
    const ushort_t* __restrict__ Thi, const ushort_t* __restrict__ Tlo,
    const ushort_t* __restrict__ Wkb, const ushort_t* __restrict__ Wob,
    const float* __restrict__ U, const float* __restrict__ Wv,
    const float* __restrict__ bq, const float* __restrict__ bk,
    ushort_t* __restrict__ Mb) {
  __shared__ __align__(128) ushort_t Th[64 * 64];
  __shared__ __align__(128) ushort_t Tl[64 * 64];
  __shared__ __align__(128) ushort_t Wks[64 * 64];
  __shared__ float Ps[64][65];
  __shared__ __align__(16) ushort_t PT[64 * 72];
  __shared__ __align__(128) ushort_t Wos[128 * 64];
  __shared__ float ush[64], wsh[64], bqs[64], bks[64];

  int b = blockIdx.x >> 4, n = (blockIdx.x >> 1) & 7, half = blockIdx.x & 1;
  int t = threadIdx.x, lane = t & 63, w = t >> 6;
  int l15 = lane & 15, l4 = lane >> 4;

  if (t < 64) ush[t] = U[b * NC + n * DH + t];
  else if (t < 128) wsh[t - 64] = Wv[b * NC + n * DH + (t - 64)];
  else if (t < 192) bqs[t - 128] = bq[n * DH + (t - 128)];
  else bks[t - 192] = bk[n * DH + (t - 192)];

  const size_t tbase = ((size_t)b * NC + n * DH) * NC;
  f32x4 zero = {0.f, 0.f, 0.f, 0.f};
  f32x4 acc[4];
#pragma unroll
  for (int i = 0; i < 4; ++i) acc[i] = zero;

  for (int kc0 = 0; kc0 < NC; kc0 += 64) {
    __syncthreads();
#pragma unroll
    for (int i = 0; i < 6; ++i) {
      int slab = w * 6 + i;
      int mat = slab >> 3, sl = slab & 7;
      int r = sl * 8 + (lane >> 3);
      int kc = (lane & 7) ^ (r & 7);
      if (mat == 0)
        gld_lds16(Thi + tbase + (size_t)r * NC + kc0 + kc * 8, &Th[sl * 512]);
      else if (mat == 1)
        gld_lds16(Tlo + tbase + (size_t)r * NC + kc0 + kc * 8, &Tl[sl * 512]);
      else
        gld_lds16(Wkb + (size_t)(n * DH + r) * NC + kc0 + kc * 8, &Wks[sl * 512]);
    }
    __syncthreads();
#pragma unroll
    for (int kf = 0; kf < 2; ++kf) {
      int rn = w * 16 + l15;
      int cn = (kf * 4 + l4) ^ (rn & 7);
      bf16x8 bvf = *(const bf16x8*)&Wks[rn * 64 + cn * 8];
#pragma unroll
      for (int i = 0; i < 4; ++i) {
        int r = i * 16 + l15;
        int c = (kf * 4 + l4) ^ (r & 7);
        bf16x8 ah = *(const bf16x8*)&Th[r * 64 + c * 8];
        bf16x8 al = *(const bf16x8*)&Tl[r * 64 + c * 8];
        acc[i] = __builtin_amdgcn_mfma_f32_16x16x32_bf16(ah, bvf, acc[i], 0, 0, 0);
        acc[i] = __builtin_amdgcn_mfma_f32_16x16x32_bf16(al, bvf, acc[i], 0, 0, 0);
      }
    }
  }
#pragma unroll
  for (int i = 0; i < 4; ++i)
#pragma unroll
    for (int rr = 0; rr < 4; ++rr) {
      int d = i * 16 + l4 * 4 + rr, e = w * 16 + l15;
      float v = acc[i][rr] + ush[d] * bks[e] + bqs[d] * (wsh[e] + 4096.f * bks[e]);
      Ps[d][e] = v * 0.125f;
    }
  __syncthreads();
  {
    int d = w * 16 + l15;
    float mx = -1e30f;
#pragma unroll
    for (int i = 0; i < 16; ++i) mx = fmaxf(mx, Ps[d][l4 * 16 + i]);
    mx = fmaxf(mx, __shfl_xor(mx, 16, 64));
    mx = fmaxf(mx, __shfl_xor(mx, 32, 64));
    float pv[16];
    float sum = 0.f;
#pragma unroll
    for (int i = 0; i < 16; ++i) {
      pv[i] = __expf(Ps[d][l4 * 16 + i] - mx);
      sum += pv[i];
    }
    sum += __shfl_xor(sum, 16, 64);
    sum += __shfl_xor(sum, 32, 64);
    float inv = 1.f / sum;
#pragma unroll
    for (int i = 0; i < 16; ++i) PT[(l4 * 16 + i) * 72 + d] = f2bf(pv[i] * inv);
  }
  for (int mi = 0; mi < 2; ++mi) {
    int mt = half * 2 + mi;
    __syncthreads();
#pragma unroll
    for (int i = 0; i < 4; ++i) {
      int slab = w * 4 + i;
      int r = slab * 8 + (lane >> 3);
      int kc = (lane & 7) ^ (r & 7);
      gld_lds16(Wob + (size_t)(mt * 128 + r) * NC + n * DH + kc * 8,
                &Wos[slab * 512]);
    }
    __syncthreads();
    f32x4 acc2[2][4];
#pragma unroll
    for (int i2 = 0; i2 < 2; ++i2)
#pragma unroll
      for (int j = 0; j < 4; ++j) acc2[i2][j] = zero;
#pragma unroll
    for (int kf = 0; kf < 2; ++kf) {
      bf16x8 bv[4];
#pragma unroll
      for (int j = 0; j < 4; ++j) {
        int e = j * 16 + l15;
        bv[j] = *(const bf16x8*)&PT[e * 72 + (kf * 4 + l4) * 8];
      }
#pragma unroll
      for (int i2 = 0; i2 < 2; ++i2) {
        int r = w * 32 + i2 * 16 + l15;
        int c = (kf * 4 + l4) ^ (r & 7);
        bf16x8 av = *(const bf16x8*)&Wos[r * 64 + c * 8];
#pragma unroll
        for (int j = 0; j < 4; ++j)
          acc2[i2][j] =
              __builtin_amdgcn_mfma_f32_16x16x32_bf16(av, bv[j], acc2[i2][j], 0, 0, 0);
      }
    }
#pragma unroll
    for (int i2 = 0; i2 < 2; ++i2)
#pragma unroll
      for (int j = 0; j < 4; ++j)
#pragma unroll
        for (int rr = 0; rr < 4; ++rr) {
          int grow = mt * 128 + w * 32 + i2 * 16 + l4 * 4 + rr;
          int gcol = n * DH + j * 16 + l15;
          float v = acc2[i2][j][rr];
          if (grow == gcol) v += 1.f;  // fold residual
          Mb[((size_t)b * NC + grow) * NC + gcol] = f2bf(v);
        }
  }
}

// ---------------- fallback fp32 vector path (round-1, known-good) -----------
#define BKt 32
#define BMt 128
#define BNt 128
#define LDTK 132

__global__ __launch_bounds__(256) void k_rowsum(const float* __restrict__ x,
                                                float* __restrict__ s) {
  int row = blockIdx.x;
  const float* xr = x + (size_t)row * NP;
  int t = threadIdx.x;
  float acc = 0.f;
  for (int i = t; i < NP / 4; i += 256) {
    float4 v = reinterpret_cast<const float4*>(xr)[i];
    acc += (v.x + v.y) + (v.z + v.w);
  }
  for (int off = 32; off > 0; off >>= 1) acc += __shfl_down(acc, off, 64);
  __shared__ float red[4];
  int lane = t & 63, wv = t >> 6;
  if (lane == 0) red[wv] = acc;
  __syncthreads();
  if (t == 0) s[row] = (red[0] + red[1]) + (red[2] + red[3]);
}

__global__ __launch_bounds__(256) void k_gemm_abT(
    const float* __restrict__ Abase, const float* __restrict__ Bbase,
    float* __restrict__ Cbase, int K, int lda, int ldb, int ldc,
    size_t sA, size_t sB, size_t sC) {
  __shared__ float As[BKt][LDTK];
  __shared__ float Bs[BKt][LDTK];
  const float* A = Abase + sA * blockIdx.z;
  const float* Bm = Bbase + sB * blockIdx.z;
  float* Cm = Cbase + sC * blockIdx.z;
  int m0 = blockIdx.y * BMt, n0 = blockIdx.x * BNt;
  int t = threadIdx.x;
  int tr = t >> 4, tc = t & 15;
  float acc[8][8];
#pragma unroll
  for (int i = 0; i < 8; ++i)
#pragma unroll
    for (int j = 0; j < 8; ++j) acc[i][j] = 0.f;
  for (int k0 = 0; k0 < K; k0 += BKt) {
#pragma unroll
    for (int it = 0; it < 4; ++it) {
      int idx = it * 256 + t;
      int r = idx >> 3, kq = idx & 7;
      float4 va = *reinterpret_cast<const float4*>(A + (size_t)(m0 + r) * lda + k0 + kq * 4);
      As[kq * 4 + 0][r] = va.x; As[kq * 4 + 1][r] = va.y;
      As[kq * 4 + 2][r] = va.z; As[kq * 4 + 3][r] = va.w;
      float4 vb = *reinterpret_cast<const float4*>(Bm + (size_t)(n0 + r) * ldb + k0 + kq * 4);
      Bs[kq * 4 + 0][r] = vb.x; Bs[kq * 4 + 1][r] = vb.y;
      Bs[kq * 4 + 2][r] = vb.z; Bs[kq * 4 + 3][r] = vb.w;
    }
    __syncthreads();
#pragma unroll
    for (int kk = 0; kk < BKt; ++kk) {
      float4 a0 = *reinterpret_cast<const float4*>(&As[kk][tr * 8]);
      float4 a1 = *reinterpret_cast<const float4*>(&As[kk][tr * 8 + 4]);
      float4 b0 = *reinterpret_cast<const float4*>(&Bs[kk][tc * 8]);
      float4 b1 = *reinterpret_cast<const float4*>(&Bs[kk][tc * 8 + 4]);
      float av[8] = {a0.x, a0.y, a0.z, a0.w, a1.x, a1.y, a1.z, a1.w};
      float bv[8] = {b0.x, b0.y, b0.z, b0.w, b1.x, b1.y, b1.z, b1.w};
#pragma unroll
      for (int i = 0; i < 8; ++i)
#pragma unroll
        for (int j = 0; j < 8; ++j) acc[i][j] += av[i] * bv[j];
    }
    __syncthreads();
  }
#pragma unroll
  for (int i = 0; i < 8; ++i) {
    float* crow = Cm + (size_t)(m0 + tr * 8 + i) * ldc + n0 + tc * 8;
    float4 c0 = {acc[i][0], acc[i][1], acc[i][2], acc[i][3]};
    float4 c1 = {acc[i][4], acc[i][5], acc[i][6], acc[i][7]};
    *reinterpret_cast<float4*>(crow) = c0;
    *reinterpret_cast<float4*>(crow + 4) = c1;
  }
}

__global__ __launch_bounds__(256) void k_gemm_ab(
    const float* __restrict__ Abase, const float* __restrict__ Bbase,
    float* __restrict__ Cbase, const float* __restrict__ bias,
    int K, int lda, int ldb, int ldc, size_t sA, size_t sB, size_t sC) {
  __shared__ float As[BKt][LDTK];
  __shared__ float Bs[BKt][LDTK];
  const float* A = Abase + sA * blockIdx.z;
  const float* Bm = Bbase + sB * blockIdx.z;
  float* Cm = Cbase + sC * blockIdx.z;
  int m0 = blockIdx.y * BMt, n0 = blockIdx.x * BNt;
  int t = threadIdx.x;
  int tr = t >> 4, tc = t & 15;
  float acc[8][8];
#pragma unroll
  for (int i = 0; i < 8; ++i)
#pragma unroll
    for (int j = 0; j < 8; ++j) acc[i][j] = 0.f;
  for (int k0 = 0; k0 < K; k0 += BKt) {
#pragma unroll
    for (int it = 0; it < 4; ++it) {
      int idx = it * 256 + t;
      int r = idx >> 3, kq = idx & 7;
      float4 va = *reinterpret_cast<const float4*>(A + (size_t)(m0 + r) * lda + k0 + kq * 4);
      As[kq * 4 + 0][r] = va.x; As[kq * 4 + 1][r] = va.y;
      As[kq * 4 + 2][r] = va.z; As[kq * 4 + 3][r] = va.w;
      int kk = idx >> 5, nq = idx & 31;
      float4 vb = *reinterpret_cast<const float4*>(Bm + (size_t)(k0 + kk) * ldb + n0 + nq * 4);
      *reinterpret_cast<float4*>(&Bs[kk][nq * 4]) = vb;
    }
    __syncthreads();
#pragma unroll
    for (int kk = 0; kk < BKt; ++kk) {
      float4 a0 = *reinterpret_cast<const float4*>(&As[kk][tr * 8]);
      float4 a1 = *reinterpret_cast<const float4*>(&As[kk][tr * 8 + 4]);
      float4 b0 = *reinterpret_cast<const float4*>(&Bs[kk][tc * 8]);
      float4 b1 = *reinterpret_cast<const float4*>(&Bs[kk][tc * 8 + 4]);
      float av[8] = {a0.x, a0.y, a0.z, a0.w, a1.x, a1.y, a1.z, a1.w};
      float bv[8] = {b0.x, b0.y, b0.z, b0.w, b1.x, b1.y, b1.z, b1.w};
#pragma unroll
      for (int i = 0; i < 8; ++i)
#pragma unroll
        for (int j = 0; j < 8; ++j) acc[i][j] += av[i] * bv[j];
    }
    __syncthreads();
  }
#pragma unroll
  for (int i = 0; i < 8; ++i) {
    int row = m0 + tr * 8 + i;
    float bb = bias ? bias[row] : 0.f;
    float* crow = Cm + (size_t)row * ldc + n0 + tc * 8;
    float4 c0 = {acc[i][0] + bb, acc[i][1] + bb, acc[i][2] + bb, acc[i][3] + bb};
    float4 c1 = {acc[i][4] + bb, acc[i][5] + bb, acc[i][6] + bb, acc[i][7] + bb};
    *reinterpret_cast<float4*>(crow) = c0;
    *reinterpret_cast<float4*>(crow + 4) = c1;
  }
}

__global__ __launch_bounds__(256) void k_att(
    const float* __restrict__ T, const float* __restrict__ wq,
    const float* __restrict__ bq, const float* __restrict__ wk,
    const float* __restrict__ bk, const float* __restrict__ wo,
    const float* __restrict__ s, float* __restrict__ Mf) {
  int b = blockIdx.x >> 3, n = blockIdx.x & 7;
  int t = threadIdx.x;
  __shared__ float sh_s[NC];
  __shared__ float sh_u[DH], sh_w[DH];
  __shared__ float L[DH][DH + 1];
  __shared__ float Ts[DH][68];
  __shared__ float Ks[DH][68];

  for (int i = t; i < NC; i += 256) sh_s[i] = s[b * NC + i];
  __syncthreads();
  if (t < 128) {
    int d = t & 63;
    const float* wrow = (t < 64 ? wq : wk) + (size_t)(n * DH + d) * NC;
    float a = 0.f;
    for (int c = 0; c < NC; ++c) a += wrow[c] * sh_s[c];
    if (t < 64) sh_u[d] = a; else sh_w[d] = a;
  }

  int d = t >> 2, eg = t & 3;
  float acc[16];
#pragma unroll
  for (int i = 0; i < 16; ++i) acc[i] = 0.f;

  for (int c0 = 0; c0 < NC; c0 += 64) {
#pragma unroll
    for (int it = 0; it < 4; ++it) {
      int idx = it * 256 + t;
      int r = idx >> 4, cq = idx & 15;
      float4 v = *reinterpret_cast<const float4*>(
          T + ((size_t)b * NC + n * DH + r) * NC + c0 + cq * 4);
      *reinterpret_cast<float4*>(&Ts[r][cq * 4]) = v;
      float4 kv = *reinterpret_cast<const float4*>(
          wk + (size_t)(n * DH + r) * NC + c0 + cq * 4);
      Ks[cq * 4 + 0][r] = kv.x; Ks[cq * 4 + 1][r] = kv.y;
      Ks[cq * 4 + 2][r] = kv.z; Ks[cq * 4 + 3][r] = kv.w;
    }
    __syncthreads();
    for (int cc = 0; cc < 64; ++cc) {
      float tv = Ts[d][cc];
      float4 k0v = *reinterpret_cast<const float4*>(&Ks[cc][eg * 16]);
      float4 k1v = *reinterpret_cast<const float4*>(&Ks[cc][eg * 16 + 4]);
      float4 k2v = *reinterpret_cast<const float4*>(&Ks[cc][eg * 16 + 8]);
      float4 k3v = *reinterpret_cast<const float4*>(&Ks[cc][eg * 16 + 12]);
      acc[0] += tv * k0v.x;  acc[1] += tv * k0v.y;
      acc[2] += tv * k0v.z;  acc[3] += tv * k0v.w;
      acc[4] += tv * k1v.x;  acc[5] += tv * k1v.y;
      acc[6] += tv * k1v.z;  acc[7] += tv * k1v.w;
      acc[8] += tv * k2v.x;  acc[9] += tv * k2v.y;
      acc[10] += tv * k2v.z; acc[11] += tv * k2v.w;
      acc[12] += tv * k3v.x; acc[13] += tv * k3v.y;
      acc[14] += tv * k3v.z; acc[15] += tv * k3v.w;
    }
    __syncthreads();
  }

  float bqd = bq[n * DH + d];
  float ud = sh_u[d];
#pragma unroll
  for (int i = 0; i < 16; ++i) {
    int e = eg * 16 + i;
    float bke = bk[n * DH + e];
    L[d][e] = (acc[i] + ud * bke + bqd * (sh_w[e] + (float)NP * bke)) * 0.125f;
  }
  __syncthreads();
  if (t < 64) {
    float mx = -1e30f;
    for (int e = 0; e < DH; ++e) mx = fmaxf(mx, L[t][e]);
    float sum = 0.f;
    for (int e = 0; e < DH; ++e) { float p = __expf(L[t][e] - mx); L[t][e] = p; sum += p; }
    float inv = 1.f / sum;
    for (int e = 0; e < DH; ++e) L[t][e] *= inv;
  }
  __syncthreads();

#pragma unroll
  for (int rep = 0; rep < 2; ++rep) {
    int o = rep * 256 + t;
    const float* worow = wo + (size_t)o * NC + n * DH;
    float wreg[64];
#pragma unroll
    for (int q = 0; q < 16; ++q) {
      float4 v = *reinterpret_cast<const float4*>(worow + q * 4);
      wreg[q * 4 + 0] = v.x; wreg[q * 4 + 1] = v.y;
      wreg[q * 4 + 2] = v.z; wreg[q * 4 + 3] = v.w;
    }
    for (int e = 0; e < DH; ++e) {
      float a = 0.f;
#pragma unroll
      for (int dd = 0; dd < DH; ++dd) a += wreg[dd] * L[dd][e];
      int col = n * DH + e;
      if (o == col) a += 1.f;
      Mf[((size_t)b * NC + o) * NC + col] = a;
    }
  }
}

extern "C" void kernel_launch(void* const* d_in, const int* in_sizes, int n_in,
                              void* d_out, int out_size, void* d_ws, size_t ws_size,
                              hipStream_t stream) {
  const float* x  = (const float*)d_in[0];
  const float* wq = (const float*)d_in[1];
  const float* bq = (const float*)d_in[2];
  const float* wk = (const float*)d_in[3];
  const float* bk = (const float*)d_in[4];
  const float* wo = (const float*)d_in[5];
  const float* bo = (const float*)d_in[6];
  float* out = (float*)d_out;
  char* ws = (char*)d_ws;

  const size_t sX = (size_t)NC * NP;  // 2097152
  const size_t sG = (size_t)NC * NC;  // 262144
  const size_t xbf_bytes = (size_t)NB * sX * 2;  // 64 MiB

  size_t off_s  = 0;                                   // 32 KiB
  size_t off_sp = 32768;                               // sPart: 2 MiB
  size_t off_xt = off_sp + (size_t)64 * NB * NC * 4;   // 64 MiB (tiled)
  size_t off_mb = off_xt + xbf_bytes;                  // 8 MiB
  size_t off_wq = off_mb + (size_t)NB * sG * 2;
  size_t off_wk = off_wq + sG * 2;
  size_t off_wo = off_wk + sG * 2;
  size_t off_u  = off_wo + sG * 2;
  size_t off_w  = off_u + 32768;
  size_t need   = off_w + 32768;

  if (ws_size >= need + 4096) {
    // ---- fast MFMA path ----
    float*    s     = (float*)(ws + off_s);
    float*    sPart = (float*)(ws + off_sp);
    ushort_t* Xt    = (ushort_t*)(ws + off_xt);
    ushort_t* Mb    = (ushort_t*)(ws + off_mb);
    ushort_t* Wqb   = (ushort_t*)(ws + off_wq);
    ushort_t* Wkb   = (ushort_t*)(ws + off_wk);
    ushort_t* Wob   = (ushort_t*)(ws + off_wo);
    float*    U     = (float*)(ws + off_u);
    float*    W     = (float*)(ws + off_w);
    char* dob = (char*)d_out;
    ushort_t* Xbf   = (ushort_t*)d_out;            // [0,64M): dead after Gram
    ushort_t* Gpart = (ushort_t*)(dob + xbf_bytes); // [64M,96M): fp16 partials
    ushort_t* Gb    = (ushort_t*)d_out;            // [0,8M) after Gram
    ushort_t* Thi   = (ushort_t*)(dob + xbf_bytes);     // [64M,72M)
    ushort_t* Tlo   = Thi + 4194304;                    // [72M,80M)

    k_cvtw<<<dim3(1024), 256, 0, stream>>>(wq, wk, wo, Wqb, Wkb, Wob);
    k_prep<<<dim3(64, 8, 16), 256, 0, stream>>>(x, Xbf, Xt, sPart);
    k_sreduce<<<dim3(32), 256, 0, stream>>>(sPart, s);
    k_uw<<<dim3(NB * NHD), 256, 0, stream>>>(wq, wk, s, U, W);
    // triangle Gram split-K=4, fp16 partials
    k_mfma_bt<<<dim3(10, 1, 64), 256, 0, stream>>>(
        Xbf, Xbf, Gpart, nullptr, NP, NP, NC,
        (long long)sX, (long long)sX, (long long)sG, NP / 4, 4, 2);
    k_reduceG<<<dim3(4, 10, 16), 256, 0, stream>>>(Gpart, Gb);
    // T_b = Wq * G_b -> split-bf16 hi/lo (G symmetric -> bt-form valid)
    k_mfma_bt<<<dim3(4, 4, 16), 256, 0, stream>>>(
        Wqb, Gb, Thi, nullptr, NC, NC, NC,
        0LL, (long long)sG, (long long)sG, NC, 3, 1);
    // logits -> softmax -> M' = Wo*blockdiag(P) + I  (bf16), 2 blocks/(b,n)
    k_fused<<<dim3(NB * NHD * 2), 256, 0, stream>>>(Thi, Tlo, Wkb, Wob, U, W,
                                                    bq, bk, Mb);
    // out = (M+I) X + bo  (n-grouped XCD decode + tiled-B + nontemporal stores)
    k_mfma_bt<<<dim3(2048), 256, 0, stream>>>(
        Mb, Xt, out, bo, NC, NC, NP,
        (long long)sG, (long long)sX, (long long)sX, NC, 1, 12);
  } else {
    // ---- fallback: round-1 fp32 vector path ----
    float* s  = (float*)ws;
    float* G  = (float*)(ws + 32768);
    float* Tm = (float*)(ws + 32768 + (size_t)NB * sG * 4);
    float* M  = G;
    k_rowsum<<<NB * NC, 256, 0, stream>>>(x, s);
    k_gemm_abT<<<dim3(4, 4, NB), 256, 0, stream>>>(x, x, G, NP, NP, NP, NC, sX, sX, sG);
    k_gemm_ab<<<dim3(4, 4, NB), 256, 0, stream>>>(wq, G, Tm, nullptr, NC, NC, NC, NC,
                                                  0, sG, sG);
    k_att<<<NB * NHD, 256, 0, stream>>>(Tm, wq, bq, wk, bk, wo, s, M);
    k_gemm_ab<<<dim3(NP / BNt, NC / BMt, NB), 256, 0, stream>>>(M, x, out, bo, NC, NC,
                                                                NP, NP, sG, sX, sX);
  }
}